// Round 4
// baseline (592.351 us; speedup 1.0000x reference)
//
#include <hip/hip_runtime.h>
#include <hip/hip_bf16.h>

typedef __bf16 bf16_t;
typedef __bf16 bf16x8 __attribute__((ext_vector_type(8)));
typedef __bf16 bf16x4v __attribute__((ext_vector_type(4)));
typedef float f32x4 __attribute__((ext_vector_type(4)));

#define HIDDEN 3584
#define SEQ 2048
#define NHEADS 28
#define NKV 4
#define HDIM 128
#define GROUPS 7
#define QKV_LD 4608
#define SCL_LOG2 (0.08838834764831845f * 1.44269504088896f)

__device__ inline f32x4 mfma16(bf16x8 a, bf16x8 b, f32x4 c) {
    return __builtin_amdgcn_mfma_f32_16x16x32_bf16(a, b, c, 0, 0, 0);
}

__device__ inline void gl_lds16(const bf16_t* g, bf16_t* l) {
    __builtin_amdgcn_global_load_lds(
        (const __attribute__((address_space(1))) void*)g,
        (__attribute__((address_space(3))) void*)l, 16, 0, 0);
}

// ---------------- fp32 -> bf16 convert ----------------
__global__ void cvt_kernel(const float* __restrict__ src, bf16_t* __restrict__ dst, int n4) {
    int i = blockIdx.x * 256 + threadIdx.x;
    if (i < n4) {
        float4 f = ((const float4*)src)[i];
        bf16x4v o;
        o.x = (bf16_t)f.x; o.y = (bf16_t)f.y; o.z = (bf16_t)f.z; o.w = (bf16_t)f.w;
        ((bf16x4v*)dst)[i] = o;
    }
}

// ---------------- bias concat (bq|bk|bv) ----------------
__global__ void bcat_kernel(const float* __restrict__ bq, const float* __restrict__ bk,
                            const float* __restrict__ bv, float* __restrict__ dst) {
    int i = blockIdx.x * 256 + threadIdx.x;
    if (i < QKV_LD) {
        float v = (i < HIDDEN) ? bq[i] : (i < HIDDEN + 512 ? bk[i - HIDDEN] : bv[i - HIDDEN - 512]);
        dst[i] = v;
    }
}

// ---------------- GEMM: C[M,N] = A[M,K] @ B[N,K]^T (+bias) ----------------
template <bool OUT_BF16>
__global__ __launch_bounds__(256) void gemm_bt(
    const bf16_t* __restrict__ A, const bf16_t* __restrict__ B,
    const float* __restrict__ bias, void* __restrict__ Cout,
    int M, int N, int K) {
    __shared__ __align__(16) bf16_t As[128 * 32];
    __shared__ __align__(16) bf16_t Bs[128 * 32];
    const int tid = threadIdx.x;
    const int w = tid >> 6, lane = tid & 63;
    const int quad = lane >> 4, l16 = lane & 15;
    const int wm = w >> 1, wn = w & 1;
    const int m0 = blockIdx.y * 128, n0 = blockIdx.x * 128;
    f32x4 acc[4][4] = {};
    for (int k0 = 0; k0 < K; k0 += 32) {
        __syncthreads();
#pragma unroll
        for (int i = 0; i < 2; ++i) {
            int ca = (w * 2 + i) * 64 + lane;
            int row = ca >> 2, kc = ca & 3;
            gl_lds16(A + (size_t)(m0 + row) * K + k0 + kc * 8, As + (size_t)(w * 2 + i) * 64 * 8);
            gl_lds16(B + (size_t)(n0 + row) * K + k0 + kc * 8, Bs + (size_t)(w * 2 + i) * 64 * 8);
        }
        __syncthreads();
        bf16x8 a[4], b[4];
#pragma unroll
        for (int i = 0; i < 4; ++i)
            a[i] = *(const bf16x8*)(As + (wm * 64 + i * 16 + l16) * 32 + quad * 8);
#pragma unroll
        for (int j = 0; j < 4; ++j)
            b[j] = *(const bf16x8*)(Bs + (wn * 64 + j * 16 + l16) * 32 + quad * 8);
#pragma unroll
        for (int i = 0; i < 4; ++i)
#pragma unroll
            for (int j = 0; j < 4; ++j)
                acc[i][j] = mfma16(a[i], b[j], acc[i][j]);
    }
#pragma unroll
    for (int i = 0; i < 4; ++i) {
#pragma unroll
        for (int j = 0; j < 4; ++j) {
            int col = n0 + wn * 64 + j * 16 + l16;
            float bv_ = bias ? bias[col] : 0.f;
#pragma unroll
            for (int r = 0; r < 4; ++r) {
                int row = m0 + wm * 64 + i * 16 + quad * 4 + r;
                float v = acc[i][j][r] + bv_;
                if (OUT_BF16) ((bf16_t*)Cout)[(size_t)row * N + col] = (bf16_t)v;
                else          ((float*)Cout)[(size_t)row * N + col] = v;
            }
        }
    }
}

// ---------------- RoPE (in-place on bf16 qkv buffer) ----------------
__global__ void rope_kernel(bf16_t* __restrict__ qkv,
                            const float* __restrict__ cosb, const float* __restrict__ sinb) {
    int t = blockIdx.x * 256 + threadIdx.x;   // SEQ * 32 * 64 total
    int d = t & 63;
    int hh = (t >> 6) & 31;
    int s = t >> 11;
    float c0 = cosb[s * 128 + d], sn0 = sinb[s * 128 + d];
    float c1 = cosb[s * 128 + d + 64], sn1 = sinb[s * 128 + d + 64];
    bf16_t* p;
    if (hh < NHEADS) p = qkv + (size_t)s * QKV_LD + hh * HDIM;
    else             p = qkv + (size_t)s * QKV_LD + HIDDEN + (hh - NHEADS) * HDIM;
    float x0 = (float)p[d], x1 = (float)p[d + 64];
    p[d]      = (bf16_t)(x0 * c0 - x1 * sn0);
    p[d + 64] = (bf16_t)(x1 * c1 + x0 * sn1);
}

// ---------------- Flash attention v4: one q-tile per block, swizzled grid ----------------
// grid (32, NHEADS); 4 waves; block handles q-tile qb = (x + 11*y) & 31 (64 rows)
// All 896 blocks co-resident at 4 blocks/CU; swizzle spreads per-CU work.
// kv fragment-row permutation: F(st,m) = 32*(st>>1) + 8*(m>>2) + 4*(st&1) + (m&3)
__global__ __launch_bounds__(256) void attn_kernel(
    const bf16_t* __restrict__ qkv, bf16_t* __restrict__ o_out) {
    __shared__ __align__(16) bf16_t Ks[64][130];   // kv x d, odd-dword row stride (65)
    __shared__ __align__(16) bf16_t Vt[128][66];   // d x kv, odd-dword row stride (33)
    const int tid = threadIdx.x;
    const int w = tid >> 6, lane = tid & 63;
    const int quad = lane >> 4, l16 = lane & 15;
    const int h = blockIdx.y, kvh = h / GROUPS;
    const int qb = (blockIdx.x + 11 * blockIdx.y) & 31;
    const bf16_t* qp = qkv + h * HDIM;
    const bf16_t* kp = qkv + HIDDEN + kvh * HDIM;
    const bf16_t* vp = qkv + HIDDEN + 512 + kvh * HDIM;
    int frow[4];
#pragma unroll
    for (int st = 0; st < 4; ++st)
        frow[st] = 32 * (st >> 1) + 8 * (l16 >> 2) + 4 * (st & 1) + (l16 & 3);

    const int ntk = qb + 1;
    const int rowq = qb * 64 + w * 16 + l16;   // this lane's q-row (as column of S^T)
    bf16x8 qa[4];
#pragma unroll
    for (int kc = 0; kc < 4; ++kc)
        qa[kc] = *(const bf16x8*)(qp + (size_t)rowq * QKV_LD + kc * 32 + quad * 8);
    f32x4 o[8] = {};
    float m_r = -1.0e30f, l_r = 0.f;

    int4 kr[4], vr[4];
    auto loadT = [&](int kv0) {
#pragma unroll
        for (int i = 0; i < 4; ++i)
            kr[i] = *(const int4*)(kp + (size_t)(kv0 + w * 4 + 16 * i + quad) * QKV_LD + l16 * 8);
#pragma unroll
        for (int i = 0; i < 4; ++i)
            vr[i] = *(const int4*)(vp + (size_t)(kv0 + lane) * QKV_LD + (w + 4 * i) * 8);
    };
    loadT(0);

    for (int it = 0; it < ntk; ++it) {
        const int kv0 = it * 64;
        __syncthreads();
        // regs -> LDS
#pragma unroll
        for (int i = 0; i < 4; ++i)
            *(int4*)&Ks[w * 4 + 16 * i + quad][l16 * 8] = kr[i];
#pragma unroll
        for (int i = 0; i < 4; ++i) {
            int c8 = w + 4 * i;
            bf16_t* ts = (bf16_t*)&vr[i];
#pragma unroll
            for (int i2 = 0; i2 < 8; ++i2) Vt[c8 * 8 + i2][lane] = ts[i2];
        }
        __syncthreads();
        if (it + 1 < ntk) loadT(kv0 + 64);   // prefetch overlaps compute below
        // S^T = K Q^T : 4 C-frags [kv(permuted) x q]
        f32x4 s[4] = {};
#pragma unroll
        for (int kc = 0; kc < 4; ++kc)
#pragma unroll
            for (int st = 0; st < 4; ++st) {
                bf16x8 kb = *(const bf16x8*)&Ks[frow[st]][kc * 32 + quad * 8];
                s[st] = mfma16(kb, qa[kc], s[st]);
            }
        // softmax (log2 domain); row stats live per-lane for q=l16
        const bool diag = (it == ntk - 1);
        float xv[4][4], mx = -1.0e30f;
#pragma unroll
        for (int st = 0; st < 4; ++st)
#pragma unroll
            for (int r = 0; r < 4; ++r) {
                int kvg = kv0 + 32 * (st >> 1) + 8 * quad + 4 * (st & 1) + r;
                float x = s[st][r] * SCL_LOG2;
                if (diag && kvg > rowq) x = -1.0e30f;
                xv[st][r] = x;
                mx = fmaxf(mx, x);
            }
        mx = fmaxf(mx, __shfl_xor(mx, 16));
        mx = fmaxf(mx, __shfl_xor(mx, 32));
        float mn = fmaxf(m_r, mx);
        float al = __builtin_amdgcn_exp2f(m_r - mn);
        m_r = mn;
        float rs = 0.f;
        bf16x8 pb0, pb1;
#pragma unroll
        for (int r = 0; r < 4; ++r) {
            float p00 = __builtin_amdgcn_exp2f(xv[0][r] - mn);
            float p01 = __builtin_amdgcn_exp2f(xv[1][r] - mn);
            float p10 = __builtin_amdgcn_exp2f(xv[2][r] - mn);
            float p11 = __builtin_amdgcn_exp2f(xv[3][r] - mn);
            rs += (p00 + p01) + (p10 + p11);
            pb0[r] = (bf16_t)p00; pb0[4 + r] = (bf16_t)p01;
            pb1[r] = (bf16_t)p10; pb1[4 + r] = (bf16_t)p11;
        }
        rs += __shfl_xor(rs, 16);
        rs += __shfl_xor(rs, 32);
        l_r = al * l_r + rs;
        // O^T = V^T P^T : rescale then accumulate (P^T feeds B directly)
#pragma unroll
        for (int dd = 0; dd < 8; ++dd) {
#pragma unroll
            for (int r = 0; r < 4; ++r) o[dd][r] *= al;
            bf16x8 va0 = *(const bf16x8*)&Vt[dd * 16 + l16][quad * 8];
            bf16x8 va1 = *(const bf16x8*)&Vt[dd * 16 + l16][32 + quad * 8];
            o[dd] = mfma16(va1, pb1, mfma16(va0, pb0, o[dd]));
        }
    }
    // epilogue: O^T C-layout -> out[q][d]; lane has 4 consecutive d for q=l16
    float inv_l = 1.0f / l_r;
#pragma unroll
    for (int dd = 0; dd < 8; ++dd) {
        bf16x4v ov;
#pragma unroll
        for (int r = 0; r < 4; ++r) ov[r] = (bf16_t)(o[dd][r] * inv_l);
        *(bf16x4v*)&o_out[(size_t)rowq * HIDDEN + h * HDIM + dd * 16 + quad * 4] = ov;
    }
}

extern "C" void kernel_launch(void* const* d_in, const int* in_sizes, int n_in,
                              void* d_out, int out_size, void* d_ws, size_t ws_size,
                              hipStream_t stream) {
    const float* hs   = (const float*)d_in[0];
    const float* cosb = (const float*)d_in[1];
    const float* sinb = (const float*)d_in[2];
    const float* Wq   = (const float*)d_in[3];
    const float* bq   = (const float*)d_in[4];
    const float* Wk   = (const float*)d_in[5];
    const float* bk   = (const float*)d_in[6];
    const float* Wv   = (const float*)d_in[7];
    const float* bv   = (const float*)d_in[8];
    const float* Wo   = (const float*)d_in[9];
    float* out = (float*)d_out;

    char* p = (char*)d_ws;
    bf16_t* hsb   = (bf16_t*)p; p += (size_t)SEQ * HIDDEN * 2;        // also reused as attn out
    bf16_t* Wqkvb = (bf16_t*)p; p += (size_t)QKV_LD * HIDDEN * 2;
    bf16_t* Wob   = (bf16_t*)p; p += (size_t)HIDDEN * HIDDEN * 2;
    bf16_t* qkvb  = (bf16_t*)p; p += (size_t)SEQ * QKV_LD * 2;
    float*  bcat  = (float*)p;  p += (size_t)QKV_LD * 4;

    auto cvt = [&](const float* s, bf16_t* d, size_t n) {
        int n4 = (int)(n / 4);
        cvt_kernel<<<(n4 + 255) / 256, 256, 0, stream>>>(s, d, n4);
    };
    cvt(hs, hsb, (size_t)SEQ * HIDDEN);
    cvt(Wq, Wqkvb, (size_t)HIDDEN * HIDDEN);
    cvt(Wk, Wqkvb + (size_t)HIDDEN * HIDDEN, (size_t)512 * HIDDEN);
    cvt(Wv, Wqkvb + (size_t)(HIDDEN + 512) * HIDDEN, (size_t)512 * HIDDEN);
    cvt(Wo, Wob, (size_t)HIDDEN * HIDDEN);
    bcat_kernel<<<(QKV_LD + 255) / 256, 256, 0, stream>>>(bq, bk, bv, bcat);

    gemm_bt<true><<<dim3(QKV_LD / 128, SEQ / 128), 256, 0, stream>>>(
        hsb, Wqkvb, bcat, qkvb, SEQ, QKV_LD, HIDDEN);

    rope_kernel<<<(SEQ * 32 * 64) / 256, 256, 0, stream>>>(qkvb, cosb, sinb);

    attn_kernel<<<dim3(32, NHEADS), 256, 0, stream>>>(qkvb, hsb);

    gemm_bt<false><<<dim3(HIDDEN / 128, SEQ / 128), 256, 0, stream>>>(
        hsb, Wob, nullptr, out, SEQ, HIDDEN, HIDDEN);
}

// Round 5
// 484.360 us; speedup vs baseline: 1.2230x; 1.2230x over previous
//
#include <hip/hip_runtime.h>
#include <hip/hip_bf16.h>

typedef __bf16 bf16_t;
typedef __bf16 bf16x8 __attribute__((ext_vector_type(8)));
typedef __bf16 bf16x4v __attribute__((ext_vector_type(4)));
typedef float f32x4 __attribute__((ext_vector_type(4)));

#define HIDDEN 3584
#define SEQ 2048
#define NHEADS 28
#define NKV 4
#define HDIM 128
#define GROUPS 7
#define QKV_LD 4608
#define SCL_LOG2 (0.08838834764831845f * 1.44269504088896f)

__device__ inline f32x4 mfma16(bf16x8 a, bf16x8 b, f32x4 c) {
    return __builtin_amdgcn_mfma_f32_16x16x32_bf16(a, b, c, 0, 0, 0);
}

__device__ inline void gl_lds16(const bf16_t* g, bf16_t* l) {
    __builtin_amdgcn_global_load_lds(
        (const __attribute__((address_space(1))) void*)g,
        (__attribute__((address_space(3))) void*)l, 16, 0, 0);
}

// ---------------- fused fp32 -> bf16 convert (all 5 tensors, 1 dispatch) ----------------
#define HS_F4   1835008   // 2048*3584/4
#define WQ_F4   3211264   // 3584*3584/4
#define WK_F4    458752   // 512*3584/4
#define WV_F4    458752
#define WO_F4   3211264
__global__ void cvt_all_kernel(const float* __restrict__ hs, const float* __restrict__ Wq,
                               const float* __restrict__ Wk, const float* __restrict__ Wv,
                               const float* __restrict__ Wo,
                               bf16_t* __restrict__ hsb, bf16_t* __restrict__ Wqkvb,
                               bf16_t* __restrict__ Wob) {
    int i = blockIdx.x * 256 + threadIdx.x;
    const float* s; bf16_t* d; int off;
    if (i < HS_F4) { s = hs; d = hsb; off = i; }
    else if (i < HS_F4 + WQ_F4) { s = Wq; d = Wqkvb; off = i - HS_F4; }
    else if (i < HS_F4 + WQ_F4 + WK_F4) { s = Wk; d = Wqkvb + 4 * (size_t)WQ_F4; off = i - HS_F4 - WQ_F4; }
    else if (i < HS_F4 + WQ_F4 + WK_F4 + WV_F4) { s = Wv; d = Wqkvb + 4 * ((size_t)WQ_F4 + WK_F4); off = i - HS_F4 - WQ_F4 - WK_F4; }
    else { s = Wo; d = Wob; off = i - HS_F4 - WQ_F4 - WK_F4 - WV_F4; }
    float4 f = ((const float4*)s)[off];
    bf16x4v o;
    o.x = (bf16_t)f.x; o.y = (bf16_t)f.y; o.z = (bf16_t)f.z; o.w = (bf16_t)f.w;
    ((bf16x4v*)d)[off] = o;
}

// ---------------- bias concat (bq|bk|bv) ----------------
__global__ void bcat_kernel(const float* __restrict__ bq, const float* __restrict__ bk,
                            const float* __restrict__ bv, float* __restrict__ dst) {
    int i = blockIdx.x * 256 + threadIdx.x;
    if (i < QKV_LD) {
        float v = (i < HIDDEN) ? bq[i] : (i < HIDDEN + 512 ? bk[i - HIDDEN] : bv[i - HIDDEN - 512]);
        dst[i] = v;
    }
}

// ---------------- GEMM: C[M,N] = A[M,K] @ B[N,K]^T (+bias) ----------------
// 128x128 tile, BK=64 staged as 2 x 32-col panels (m97 geometry per panel).
template <bool OUT_BF16>
__global__ __launch_bounds__(256) void gemm_bt(
    const bf16_t* __restrict__ A, const bf16_t* __restrict__ B,
    const float* __restrict__ bias, void* __restrict__ Cout,
    int M, int N, int K) {
    __shared__ __align__(16) bf16_t As[2][128 * 32];
    __shared__ __align__(16) bf16_t Bs[2][128 * 32];
    const int tid = threadIdx.x;
    const int w = tid >> 6, lane = tid & 63;
    const int quad = lane >> 4, l16 = lane & 15;
    const int wm = w >> 1, wn = w & 1;
    const int m0 = blockIdx.y * 128, n0 = blockIdx.x * 128;
    f32x4 acc[4][4] = {};
    for (int k0 = 0; k0 < K; k0 += 64) {
        __syncthreads();
#pragma unroll
        for (int p = 0; p < 2; ++p)
#pragma unroll
            for (int i = 0; i < 2; ++i) {
                int ca = (w * 2 + i) * 64 + lane;          // chunk 0..511 within panel
                int row = ca >> 2, kc = ca & 3;
                gl_lds16(A + (size_t)(m0 + row) * K + k0 + p * 32 + kc * 8,
                         As[p] + (size_t)(w * 2 + i) * 512);
                gl_lds16(B + (size_t)(n0 + row) * K + k0 + p * 32 + kc * 8,
                         Bs[p] + (size_t)(w * 2 + i) * 512);
            }
        __syncthreads();
#pragma unroll
        for (int p = 0; p < 2; ++p) {
            bf16x8 a[4], b[4];
#pragma unroll
            for (int i = 0; i < 4; ++i)
                a[i] = *(const bf16x8*)(As[p] + (wm * 64 + i * 16 + l16) * 32 + quad * 8);
#pragma unroll
            for (int j = 0; j < 4; ++j)
                b[j] = *(const bf16x8*)(Bs[p] + (wn * 64 + j * 16 + l16) * 32 + quad * 8);
#pragma unroll
            for (int i = 0; i < 4; ++i)
#pragma unroll
                for (int j = 0; j < 4; ++j)
                    acc[i][j] = mfma16(a[i], b[j], acc[i][j]);
        }
    }
#pragma unroll
    for (int i = 0; i < 4; ++i) {
#pragma unroll
        for (int j = 0; j < 4; ++j) {
            int col = n0 + wn * 64 + j * 16 + l16;
            float bv_ = bias ? bias[col] : 0.f;
#pragma unroll
            for (int r = 0; r < 4; ++r) {
                int row = m0 + wm * 64 + i * 16 + quad * 4 + r;
                float v = acc[i][j][r] + bv_;
                if (OUT_BF16) ((bf16_t*)Cout)[(size_t)row * N + col] = (bf16_t)v;
                else          ((float*)Cout)[(size_t)row * N + col] = v;
            }
        }
    }
}

// ---------------- RoPE (in-place on bf16 qkv buffer) ----------------
__global__ void rope_kernel(bf16_t* __restrict__ qkv,
                            const float* __restrict__ cosb, const float* __restrict__ sinb) {
    int t = blockIdx.x * 256 + threadIdx.x;   // SEQ * 32 * 64 total
    int d = t & 63;
    int hh = (t >> 6) & 31;
    int s = t >> 11;
    float c0 = cosb[s * 128 + d], sn0 = sinb[s * 128 + d];
    float c1 = cosb[s * 128 + d + 64], sn1 = sinb[s * 128 + d + 64];
    bf16_t* p;
    if (hh < NHEADS) p = qkv + (size_t)s * QKV_LD + hh * HDIM;
    else             p = qkv + (size_t)s * QKV_LD + HIDDEN + (hh - NHEADS) * HDIM;
    float x0 = (float)p[d], x1 = (float)p[d + 64];
    p[d]      = (bf16_t)(x0 * c0 - x1 * sn0);
    p[d + 64] = (bf16_t)(x1 * c1 + x0 * sn1);
}

// ---------------- Flash attention (R3 structure): S^T form, paired q-tiles ----------------
// grid (16, NHEADS); 4 waves; block p handles q-tiles {p, 31-p} (64 rows each)
// kv fragment-row permutation: F(st,m) = 32*(st>>1) + 8*(m>>2) + 4*(st&1) + (m&3)
__global__ __launch_bounds__(256) void attn_kernel(
    const bf16_t* __restrict__ qkv, bf16_t* __restrict__ o_out) {
    __shared__ __align__(16) bf16_t Ks[64][130];   // kv x d, odd-dword row stride (65)
    __shared__ __align__(16) bf16_t Vt[128][66];   // d x kv, odd-dword row stride (33)
    const int tid = threadIdx.x;
    const int w = tid >> 6, lane = tid & 63;
    const int quad = lane >> 4, l16 = lane & 15;
    const int h = blockIdx.y, kvh = h / GROUPS;
    const int pr = blockIdx.x;
    const bf16_t* qp = qkv + h * HDIM;
    const bf16_t* kp = qkv + HIDDEN + kvh * HDIM;
    const bf16_t* vp = qkv + HIDDEN + 512 + kvh * HDIM;
    int frow[4];
#pragma unroll
    for (int st = 0; st < 4; ++st)
        frow[st] = 32 * (st >> 1) + 8 * (l16 >> 2) + 4 * (st & 1) + (l16 & 3);

    for (int sub = 0; sub < 2; ++sub) {
        const int qb = sub ? (31 - pr) : pr;
        const int ntk = qb + 1;
        const int rowq = qb * 64 + w * 16 + l16;   // this lane's q-row (as column of S^T)
        bf16x8 qa[4];
#pragma unroll
        for (int kc = 0; kc < 4; ++kc)
            qa[kc] = *(const bf16x8*)(qp + (size_t)rowq * QKV_LD + kc * 32 + quad * 8);
        f32x4 o[8] = {};
        float m_r = -1.0e30f, l_r = 0.f;

        int4 kr[4], vr[4];
        auto loadT = [&](int kv0) {
#pragma unroll
            for (int i = 0; i < 4; ++i)
                kr[i] = *(const int4*)(kp + (size_t)(kv0 + w * 4 + 16 * i + quad) * QKV_LD + l16 * 8);
#pragma unroll
            for (int i = 0; i < 4; ++i)
                vr[i] = *(const int4*)(vp + (size_t)(kv0 + lane) * QKV_LD + (w + 4 * i) * 8);
        };
        loadT(0);

        for (int it = 0; it < ntk; ++it) {
            const int kv0 = it * 64;
            __syncthreads();
#pragma unroll
            for (int i = 0; i < 4; ++i)
                *(int4*)&Ks[w * 4 + 16 * i + quad][l16 * 8] = kr[i];
#pragma unroll
            for (int i = 0; i < 4; ++i) {
                int c8 = w + 4 * i;
                bf16_t* ts = (bf16_t*)&vr[i];
#pragma unroll
                for (int i2 = 0; i2 < 8; ++i2) Vt[c8 * 8 + i2][lane] = ts[i2];
            }
            __syncthreads();
            if (it + 1 < ntk) loadT(kv0 + 64);   // prefetch overlaps compute below
            f32x4 s[4] = {};
#pragma unroll
            for (int kc = 0; kc < 4; ++kc)
#pragma unroll
                for (int st = 0; st < 4; ++st) {
                    bf16x8 kb = *(const bf16x8*)&Ks[frow[st]][kc * 32 + quad * 8];
                    s[st] = mfma16(kb, qa[kc], s[st]);
                }
            const bool diag = (it == ntk - 1);
            float xv[4][4], mx = -1.0e30f;
#pragma unroll
            for (int st = 0; st < 4; ++st)
#pragma unroll
                for (int r = 0; r < 4; ++r) {
                    int kvg = kv0 + 32 * (st >> 1) + 8 * quad + 4 * (st & 1) + r;
                    float x = s[st][r] * SCL_LOG2;
                    if (diag && kvg > rowq) x = -1.0e30f;
                    xv[st][r] = x;
                    mx = fmaxf(mx, x);
                }
            mx = fmaxf(mx, __shfl_xor(mx, 16));
            mx = fmaxf(mx, __shfl_xor(mx, 32));
            float mn = fmaxf(m_r, mx);
            float al = __builtin_amdgcn_exp2f(m_r - mn);
            m_r = mn;
            float rs = 0.f;
            bf16x8 pb0, pb1;
#pragma unroll
            for (int r = 0; r < 4; ++r) {
                float p00 = __builtin_amdgcn_exp2f(xv[0][r] - mn);
                float p01 = __builtin_amdgcn_exp2f(xv[1][r] - mn);
                float p10 = __builtin_amdgcn_exp2f(xv[2][r] - mn);
                float p11 = __builtin_amdgcn_exp2f(xv[3][r] - mn);
                rs += (p00 + p01) + (p10 + p11);
                pb0[r] = (bf16_t)p00; pb0[4 + r] = (bf16_t)p01;
                pb1[r] = (bf16_t)p10; pb1[4 + r] = (bf16_t)p11;
            }
            rs += __shfl_xor(rs, 16);
            rs += __shfl_xor(rs, 32);
            l_r = al * l_r + rs;
#pragma unroll
            for (int dd = 0; dd < 8; ++dd) {
#pragma unroll
                for (int r = 0; r < 4; ++r) o[dd][r] *= al;
                bf16x8 va0 = *(const bf16x8*)&Vt[dd * 16 + l16][quad * 8];
                bf16x8 va1 = *(const bf16x8*)&Vt[dd * 16 + l16][32 + quad * 8];
                o[dd] = mfma16(va1, pb1, mfma16(va0, pb0, o[dd]));
            }
        }
        float inv_l = 1.0f / l_r;
#pragma unroll
        for (int dd = 0; dd < 8; ++dd) {
            bf16x4v ov;
#pragma unroll
            for (int r = 0; r < 4; ++r) ov[r] = (bf16_t)(o[dd][r] * inv_l);
            *(bf16x4v*)&o_out[(size_t)rowq * HIDDEN + h * HDIM + dd * 16 + quad * 4] = ov;
        }
    }
}

extern "C" void kernel_launch(void* const* d_in, const int* in_sizes, int n_in,
                              void* d_out, int out_size, void* d_ws, size_t ws_size,
                              hipStream_t stream) {
    const float* hs   = (const float*)d_in[0];
    const float* cosb = (const float*)d_in[1];
    const float* sinb = (const float*)d_in[2];
    const float* Wq   = (const float*)d_in[3];
    const float* bq   = (const float*)d_in[4];
    const float* Wk   = (const float*)d_in[5];
    const float* bk   = (const float*)d_in[6];
    const float* Wv   = (const float*)d_in[7];
    const float* bv   = (const float*)d_in[8];
    const float* Wo   = (const float*)d_in[9];
    float* out = (float*)d_out;

    char* p = (char*)d_ws;
    bf16_t* hsb   = (bf16_t*)p; p += (size_t)SEQ * HIDDEN * 2;        // also reused as attn out
    bf16_t* Wqkvb = (bf16_t*)p; p += (size_t)QKV_LD * HIDDEN * 2;
    bf16_t* Wob   = (bf16_t*)p; p += (size_t)HIDDEN * HIDDEN * 2;
    bf16_t* qkvb  = (bf16_t*)p; p += (size_t)SEQ * QKV_LD * 2;
    float*  bcat  = (float*)p;  p += (size_t)QKV_LD * 4;

    const int total_f4 = HS_F4 + WQ_F4 + WK_F4 + WV_F4 + WO_F4;
    cvt_all_kernel<<<(total_f4 + 255) / 256, 256, 0, stream>>>(
        hs, Wq, Wk, Wv, Wo, hsb, Wqkvb, Wob);
    bcat_kernel<<<(QKV_LD + 255) / 256, 256, 0, stream>>>(bq, bk, bv, bcat);

    gemm_bt<true><<<dim3(QKV_LD / 128, SEQ / 128), 256, 0, stream>>>(
        hsb, Wqkvb, bcat, qkvb, SEQ, QKV_LD, HIDDEN);

    rope_kernel<<<(SEQ * 32 * 64) / 256, 256, 0, stream>>>(qkvb, cosb, sinb);

    attn_kernel<<<dim3(16, NHEADS), 256, 0, stream>>>(qkvb, hsb);

    gemm_bt<false><<<dim3(HIDDEN / 128, SEQ / 128), 256, 0, stream>>>(
        hsb, Wob, nullptr, out, SEQ, HIDDEN, HIDDEN);
}